// Round 10
// baseline (285.232 us; speedup 1.0000x reference)
//
#include <hip/hip_runtime.h>

#define F 128
#define NBA 512        // D-side binning blocks
#define NBS 128        // S-side binning blocks
#define COARSE 256     // coarse buckets = node >> 8  (assumes N = 65536)
#define CAP_BIN 4864   // slot capacity per bucket, pre-sort (mean 4096, 12 sigma)
#define CAP_CSR 5632   // slot capacity per bucket, post-sort w/ per-row 4-align pads

typedef unsigned int uint;
typedef unsigned short ushort;
typedef unsigned char uchar;
typedef __attribute__((ext_vector_type(8))) short short8;
typedef __attribute__((ext_vector_type(8))) unsigned short ushort8;
typedef __attribute__((ext_vector_type(4))) float floatx4;

__device__ __forceinline__ ushort f2bf(float f) {
  uint u = __float_as_uint(f);
  u += 0x7fffu + ((u >> 16) & 1u);   // round-to-nearest-even
  return (ushort)(u >> 16);
}

// ---------------- W prep: fp32 [k][n] -> bf16 [n][k] (once, tiny) ----------------
__global__ __launch_bounds__(256) void w_prep(const float* __restrict__ W1,
                                              const float* __restrict__ W2,
                                              ushort* __restrict__ W1t,
                                              ushort* __restrict__ W2t) {
  int b = blockIdx.x;                         // 0..127
  const float* W = (b < 64) ? W1 : W2;
  ushort* Wt = (b < 64) ? W1t : W2t;
  int idx = (b & 63) * 256 + threadIdx.x;     // 0..16383
  int k = idx >> 7, n = idx & 127;
  Wt[n * F + k] = f2bf(W[idx]);
}

// ---------------- single-pass slotted binning ----------------
// Blocks [0,NBA): dst -> uint2{payload, fineKey} into slotted D regions.
// Blocks [NBA,NBA+NBS): src -> 1 B fine keys into S regions.
// Count: per-wave sub-histograms. Scatter: per-wave exclusive cursors
// (LDS atomic contention only within one wave).
__global__ __launch_bounds__(256) void bin_edges(
    const int* __restrict__ src, const int* __restrict__ dst,
    const float* __restrict__ ew, int E,
    int* __restrict__ cursorD, int* __restrict__ cursorS,
    uint2* __restrict__ slotD, uchar* __restrict__ srcF) {
  __shared__ int cnt[4][COARSE];
  bool isD = blockIdx.x < NBA;
  int blk = isD ? blockIdx.x : blockIdx.x - NBA;
  int nblk = isD ? NBA : NBS;
  const int* key = isD ? dst : src;
  int* cursor = isD ? cursorD : cursorS;
  int wave = threadIdx.x >> 6;
  for (int i = threadIdx.x; i < 4 * COARSE; i += 256) ((int*)cnt)[i] = 0;
  __syncthreads();
  int chunk = (E + nblk - 1) / nblk;
  int s0 = blk * chunk, s1 = min(E, s0 + chunk);
  for (int i = s0 + threadIdx.x; i < s1; i += 256)
    atomicAdd(&cnt[wave][key[i] >> 8], 1);
  __syncthreads();
  if (threadIdx.x < COARSE) {
    int b = threadIdx.x;
    int c0 = cnt[0][b], c1 = cnt[1][b], c2 = cnt[2][b], c3 = cnt[3][b];
    int tot = c0 + c1 + c2 + c3;
    int base = tot ? atomicAdd(&cursor[b], tot) : 0;   // bin-relative base
    cnt[0][b] = base;
    cnt[1][b] = base + c0;
    cnt[2][b] = base + c0 + c1;
    cnt[3][b] = base + c0 + c1 + c2;
  }
  __syncthreads();
  if (isD) {
    for (int i = s0 + threadIdx.x; i < s1; i += 256) {
      int d = dst[i];
      int bin = d >> 8;
      int p = atomicAdd(&cnt[wave][bin], 1);   // intra-wave contention only
      if (p < CAP_BIN) {
        uint2 v;
        v.x = (uint)(src[i] & 0xffff) | ((uint)f2bf(ew[i]) << 16);
        v.y = (uint)(d & 255);
        slotD[(size_t)bin * CAP_BIN + p] = v;
      }
    }
  } else {
    for (int i = s0 + threadIdx.x; i < s1; i += 256) {
      int s = src[i];
      int bin = s >> 8;
      int p = atomicAdd(&cnt[wave][bin], 1);
      if (p < CAP_BIN) srcF[(size_t)bin * CAP_BIN + p] = (uchar)(s & 255);
    }
  }
}

// ---------------- per-bucket fine sort -> 4-aligned CSR rows ----------------
// Blocks [0,COARSE): D phase. Blocks [COARSE,2*COARSE): S phase (outNorm).
__global__ __launch_bounds__(1024) void bucket_csr(
    const uint2* __restrict__ slotD, const int* __restrict__ cursorD,
    int2* __restrict__ rowRange, float* __restrict__ inNorm, uint* __restrict__ csr,
    const uchar* __restrict__ srcF, const int* __restrict__ cursorS,
    float* __restrict__ outNorm) {
  __shared__ int hist[256], base[256], cur[256];
  int t = threadIdx.x;
  if (blockIdx.x >= COARSE) {   // ---- S phase: outNorm ----
    int b = blockIdx.x - COARSE;
    int lo = b * CAP_BIN;
    int cntS = min(cursorS[b], CAP_BIN);
    if (t < 256) hist[t] = 0;
    __syncthreads();
    for (int i = lo + t; i < lo + cntS; i += 1024)
      atomicAdd(&hist[srcF[i]], 1);
    __syncthreads();
    if (t < 256) outNorm[b * 256 + t] = rsqrtf((float)max(hist[t], 1));
    return;
  }
  // ---- D phase ----
  int b = blockIdx.x;
  int lo = b * CAP_BIN;
  int cntD = min(cursorD[b], CAP_BIN);
  int hi = lo + cntD;
  if (t < 256) hist[t] = 0;
  __syncthreads();
  for (int i = lo + t; i < hi; i += 1024)
    atomicAdd(&hist[slotD[i].y], 1);
  __syncthreads();
  if (t < 256) base[t] = (hist[t] + 3) & ~3;
  __syncthreads();
  for (int off = 1; off < 256; off <<= 1) {
    int x = 0;
    if (t < 256 && t >= off) x = base[t - off];
    __syncthreads();
    if (t < 256) base[t] += x;
    __syncthreads();
  }
  if (t < 256) {
    int v = hist[t];
    int sz4 = (v + 3) & ~3;
    int st = b * CAP_CSR + base[t] - sz4;
    base[t] = st;
    cur[t] = 0;
    int node = b * 256 + t;
    rowRange[node] = make_int2(st, v);
    inNorm[node] = rsqrtf((float)max(v, 1));
  }
  __syncthreads();
  for (int i = lo + t; i < hi; i += 1024) {
    uint2 v = slotD[i];
    int fine = v.y;
    int p = base[fine] + atomicAdd(&cur[fine], 1);
    csr[p] = v.x;
  }
}

// ---------------- MFMA GEMM ----------------
template <bool BF16IN>
__global__ __launch_bounds__(256) void gemm_mfma(
    const void* __restrict__ Xv, const float* __restrict__ scale,
    const ushort* __restrict__ Wt, ushort* __restrict__ Y) {
  __shared__ ushort sA[128 * 136];
  __shared__ ushort sB[128 * 136];
  int t = threadIdx.x;
  int row0 = blockIdx.x * 128;

  {  // stage A
    int r = t >> 1, hf = t & 1;
    ushort* ap = sA + r * 136 + hf * 64;
    if (BF16IN) {
      const ushort* xp = (const ushort*)Xv + (size_t)(row0 + r) * F + hf * 64;
#pragma unroll
      for (int j = 0; j < 8; ++j)
        *(ushort8*)(ap + j * 8) = *(const ushort8*)(xp + j * 8);
    } else {
      const float* xp = (const float*)Xv + (size_t)(row0 + r) * F + hf * 64;
      float s = scale[row0 + r];
#pragma unroll
      for (int j = 0; j < 8; ++j) {
        float4 v0 = *(const float4*)(xp + j * 8);
        float4 v1 = *(const float4*)(xp + j * 8 + 4);
        ushort8 o;
        o[0] = f2bf(v0.x * s); o[1] = f2bf(v0.y * s); o[2] = f2bf(v0.z * s); o[3] = f2bf(v0.w * s);
        o[4] = f2bf(v1.x * s); o[5] = f2bf(v1.y * s); o[6] = f2bf(v1.z * s); o[7] = f2bf(v1.w * s);
        *(ushort8*)(ap + j * 8) = o;
      }
    }
  }
  {  // stage B
    int n = t >> 1, hf = t & 1;
    const ushort* wp = Wt + n * F + hf * 64;
    ushort* bp = sB + n * 136 + hf * 64;
#pragma unroll
    for (int j = 0; j < 8; ++j)
      *(ushort8*)(bp + j * 8) = *(const ushort8*)(wp + j * 8);
  }
  __syncthreads();

  int lane = t & 63, wave = t >> 6;
  int quad = lane >> 4, l16 = lane & 15;
  int mrow0 = wave * 32;

  floatx4 acc[2][8];
#pragma unroll
  for (int a = 0; a < 2; ++a)
#pragma unroll
    for (int c = 0; c < 8; ++c) acc[a][c] = (floatx4){0.f, 0.f, 0.f, 0.f};

#pragma unroll
  for (int kc = 0; kc < 128; kc += 32) {
    short8 afrag[2], bfrag[8];
#pragma unroll
    for (int a = 0; a < 2; ++a)
      afrag[a] = *(const short8*)(sA + (mrow0 + a * 16 + l16) * 136 + kc + quad * 8);
#pragma unroll
    for (int c = 0; c < 8; ++c)
      bfrag[c] = *(const short8*)(sB + (c * 16 + l16) * 136 + kc + quad * 8);
#pragma unroll
    for (int a = 0; a < 2; ++a)
#pragma unroll
      for (int c = 0; c < 8; ++c)
        acc[a][c] = __builtin_amdgcn_mfma_f32_16x16x32_bf16(afrag[a], bfrag[c], acc[a][c], 0, 0, 0);
  }

#pragma unroll
  for (int a = 0; a < 2; ++a)
#pragma unroll
    for (int c = 0; c < 8; ++c)
#pragma unroll
      for (int r = 0; r < 4; ++r) {
        int row = row0 + mrow0 + a * 16 + quad * 4 + r;
        int col = c * 16 + l16;
        Y[(size_t)row * F + col] = f2bf(acc[a][c][r]);
      }
}

// ---------------- SpMM v5: half-wave paired gather ----------------
// One wave per node. Lanes 0-31 gather even edges, 32-63 odd edges; each lane
// loads uint2 (dims 4*l32..4*l32+3). One dwordx2 instruction covers 2 edges.
// Cross-half shfl_xor(32) reduce at the end; half 0 stores.

template <bool EW, bool NB, bool RELU, bool PS, bool OUT_BF16>
__global__ __launch_bounds__(256) void spmm(
    const ushort* __restrict__ hb, const int2* __restrict__ rowRange,
    const uint* __restrict__ csr, const float* __restrict__ inNorm,
    const float* __restrict__ bias, const float* __restrict__ postScale,
    void* __restrict__ outv) {
  int node = blockIdx.x * 4 + (threadIdx.x >> 6);
  int lane = threadIdx.x & 63;
  int half = lane >> 5;          // 0: even edges, 1: odd edges
  int l32 = lane & 31;
  int2 rr = rowRange[node];
  int base = rr.x, len = rr.y;

  float a0 = 0.f, a1 = 0.f, a2 = 0.f, a3 = 0.f;
  float b0 = 0.f, b1v = 0.f, b2v = 0.f, b3 = 0.f;

#define PAIR(elo, ehi, A0, A1, A2, A3)                                          \
  {                                                                             \
    uint es = half ? (ehi) : (elo);                                             \
    uint2 w = *(const uint2*)(hb + ((size_t)(es & 0xffffu) << 7) + l32 * 4);    \
    float q = EW ? __uint_as_float(es & 0xffff0000u) : 1.f;                     \
    A0 = fmaf(__uint_as_float(w.x << 16), q, A0);                               \
    A1 = fmaf(__uint_as_float(w.x & 0xffff0000u), q, A1);                       \
    A2 = fmaf(__uint_as_float(w.y << 16), q, A2);                               \
    A3 = fmaf(__uint_as_float(w.y & 0xffff0000u), q, A3);                       \
  }

  int i = 0;
  for (; i + 8 <= len; i += 8) {
    uint4 c0 = *(const uint4*)(csr + base + i);
    uint4 c1 = *(const uint4*)(csr + base + i + 4);
    PAIR(c0.x, c0.y, a0, a1, a2, a3)
    PAIR(c0.z, c0.w, b0, b1v, b2v, b3)
    PAIR(c1.x, c1.y, a0, a1, a2, a3)
    PAIR(c1.z, c1.w, b0, b1v, b2v, b3)
  }
  if (i + 4 <= len) {
    uint4 c = *(const uint4*)(csr + base + i);
    PAIR(c.x, c.y, a0, a1, a2, a3)
    PAIR(c.z, c.w, b0, b1v, b2v, b3)
    i += 4;
  }
  int r = len - i;   // 0..3; row padded to mult-of-4 -> uint4 read safe, pads
  if (r > 0) {       // are garbage but always index inside the 16 MB table.
    uint4 c = *(const uint4*)(csr + base + i);
    {  // pair 0: edges i (half0), i+1 (half1)
      uint es = half ? c.y : c.x;
      int k = i + half;
      uint2 w = *(const uint2*)(hb + ((size_t)(es & 0xffffu) << 7) + l32 * 4);
      float q = EW ? __uint_as_float(es & 0xffff0000u) : 1.f;
      q = (k < len) ? q : 0.f;
      a0 = fmaf(__uint_as_float(w.x << 16), q, a0);
      a1 = fmaf(__uint_as_float(w.x & 0xffff0000u), q, a1);
      a2 = fmaf(__uint_as_float(w.y << 16), q, a2);
      a3 = fmaf(__uint_as_float(w.y & 0xffff0000u), q, a3);
    }
    if (r > 2) {  // pair 1: edge i+2 (half0), i+3 (half1, maybe pad)
      uint es = half ? c.w : c.z;
      int k = i + 2 + half;
      uint2 w = *(const uint2*)(hb + ((size_t)(es & 0xffffu) << 7) + l32 * 4);
      float q = EW ? __uint_as_float(es & 0xffff0000u) : 1.f;
      q = (k < len) ? q : 0.f;
      b0 = fmaf(__uint_as_float(w.x << 16), q, b0);
      b1v = fmaf(__uint_as_float(w.x & 0xffff0000u), q, b1v);
      b2v = fmaf(__uint_as_float(w.y << 16), q, b2v);
      b3 = fmaf(__uint_as_float(w.y & 0xffff0000u), q, b3);
    }
  }
#undef PAIR
  float r0 = a0 + b0, r1 = a1 + b1v, r2 = a2 + b2v, r3 = a3 + b3;
  // cross-half reduction (lane ^ 32)
  r0 += __shfl_xor(r0, 32, 64);
  r1 += __shfl_xor(r1, 32, 64);
  r2 += __shfl_xor(r2, 32, 64);
  r3 += __shfl_xor(r3, 32, 64);
  if (NB) {
    float sc = inNorm[node];
    float4 bv = *((const float4*)bias + l32);
    r0 = fmaf(r0, sc, bv.x);
    r1 = fmaf(r1, sc, bv.y);
    r2 = fmaf(r2, sc, bv.z);
    r3 = fmaf(r3, sc, bv.w);
    if (RELU) {
      r0 = fmaxf(r0, 0.f); r1 = fmaxf(r1, 0.f);
      r2 = fmaxf(r2, 0.f); r3 = fmaxf(r3, 0.f);
    }
    if (PS) { float o = postScale[node]; r0 *= o; r1 *= o; r2 *= o; r3 *= o; }
  }
  if (half == 0) {
    if (OUT_BF16) {
      uint2 p;
      p.x = ((uint)f2bf(r1) << 16) | (uint)f2bf(r0);
      p.y = ((uint)f2bf(r3) << 16) | (uint)f2bf(r2);
      *((uint2*)outv + ((size_t)node << 5) + l32) = p;
    } else {
      float4 rv = {r0, r1, r2, r3};
      *((float4*)outv + ((size_t)node << 5) + l32) = rv;
    }
  }
}

// ---------------- launch ----------------

extern "C" void kernel_launch(void* const* d_in, const int* in_sizes, int n_in,
                              void* d_out, int out_size, void* d_ws, size_t ws_size,
                              hipStream_t stream) {
  const float* feat = (const float*)d_in[0];
  const float* ew   = (const float*)d_in[1];
  const float* W1   = (const float*)d_in[2];
  const float* b1   = (const float*)d_in[3];
  const float* W2   = (const float*)d_in[4];
  const float* b2   = (const float*)d_in[5];
  const int*   src  = (const int*)d_in[6];
  const int*   dst  = (const int*)d_in[7];
  const int N = in_sizes[0] / F;   // 65536
  const int E = in_sizes[6];
  float* out = (float*)d_out;

  char* ws = (char*)d_ws;
  size_t off = 0;
  auto alloc = [&](size_t bytes) {
    void* p = ws + off;
    off += (bytes + 255) & ~(size_t)255;
    return p;
  };
  int2*   rowRange = (int2*)alloc((size_t)N * 8);
  float*  inNorm   = (float*)alloc((size_t)N * 4);
  float*  outNorm  = (float*)alloc((size_t)N * 4);
  ushort* W1t      = (ushort*)alloc((size_t)F * F * 2);
  ushort* W2t      = (ushort*)alloc((size_t)F * F * 2);
  int*    cursorD  = (int*)alloc(COARSE * 4);
  int*    cursorS  = (int*)alloc(COARSE * 4);
  uint*   csr      = (uint*)alloc((size_t)COARSE * CAP_CSR * 4);
  ushort* bufAb    = (ushort*)alloc((size_t)N * F * 2);
  ushort* bufBb    = (ushort*)alloc((size_t)N * F * 2);
  ushort* bufCb    = (ushort*)alloc((size_t)N * F * 2);
  if (off > ws_size) return;

  uint2* slotD;
  uchar* srcF;
  {
    char* tp = (char*)bufBb;
    size_t toff = 0;
    auto talloc = [&](size_t bytes) {
      void* p = tp + toff;
      toff += (bytes + 255) & ~(size_t)255;
      return p;
    };
    slotD = (uint2*)talloc((size_t)COARSE * CAP_BIN * 8);
    srcF  = (uchar*)talloc((size_t)COARSE * CAP_BIN);
  }

  hipMemsetAsync(cursorD, 0, 2 * COARSE * 4, stream);
  w_prep<<<128, 256, 0, stream>>>(W1, W2, W1t, W2t);
  bin_edges<<<NBA + NBS, 256, 0, stream>>>(src, dst, ew, E, cursorD, cursorS, slotD, srcF);
  bucket_csr<<<2 * COARSE, 1024, 0, stream>>>(slotD, cursorD, rowRange, inNorm, csr,
                                              srcF, cursorS, outNorm);

  // layer 1: h1pre = bf16( relu(SpMM(bf16((feat*outNorm)@W1)) * inNorm + b1) * outNorm )
  gemm_mfma<false><<<N / 128, 256, 0, stream>>>(feat, outNorm, W1t, bufAb);
  spmm<false, true, true, true, true><<<N / 4, 256, 0, stream>>>(
      bufAb, rowRange, csr, inNorm, b1, outNorm, bufBb);
  // layer 2: h2 = bf16( SpMM(bf16(h1pre@W2)) * inNorm + b2 )
  gemm_mfma<true><<<N / 128, 256, 0, stream>>>(bufBb, nullptr, W2t, bufAb);
  spmm<false, true, false, false, true><<<N / 4, 256, 0, stream>>>(
      bufAb, rowRange, csr, inNorm, b2, nullptr, bufCb);
  // final: out = segment_sum(h2[src] * eweight, dst)   [fp32 out]
  spmm<true, false, false, false, false><<<N / 4, 256, 0, stream>>>(
      bufCb, rowRange, csr, nullptr, nullptr, nullptr, out);
}

// Round 11
// 275.464 us; speedup vs baseline: 1.0355x; 1.0355x over previous
//
#include <hip/hip_runtime.h>

#define F 128
#define NBA 512        // D-side binning blocks
#define NBS 128        // S-side binning blocks
#define COARSE 256     // coarse buckets = node >> 8  (assumes N = 65536)
#define CAP_BIN 4864   // slot capacity per bucket, pre-sort (mean 4096, 12 sigma)
#define CAP_CSR 5632   // slot capacity per bucket, post-sort w/ per-row 4-align pads

typedef unsigned int uint;
typedef unsigned short ushort;
typedef unsigned char uchar;
typedef __attribute__((ext_vector_type(8))) short short8;
typedef __attribute__((ext_vector_type(8))) unsigned short ushort8;
typedef __attribute__((ext_vector_type(4))) float floatx4;

__device__ __forceinline__ ushort f2bf(float f) {
  uint u = __float_as_uint(f);
  u += 0x7fffu + ((u >> 16) & 1u);   // round-to-nearest-even
  return (ushort)(u >> 16);
}

// ---------------- W prep + cursor zeroing (once, tiny) ----------------
__global__ __launch_bounds__(256) void w_prep(const float* __restrict__ W1,
                                              const float* __restrict__ W2,
                                              ushort* __restrict__ W1t,
                                              ushort* __restrict__ W2t,
                                              int* __restrict__ cursorD,
                                              int* __restrict__ cursorS) {
  int b = blockIdx.x;                         // 0..127
  if (b == 0) cursorD[threadIdx.x] = 0;       // COARSE == 256 == blockDim
  if (b == 1) cursorS[threadIdx.x] = 0;
  const float* W = (b < 64) ? W1 : W2;
  ushort* Wt = (b < 64) ? W1t : W2t;
  int idx = (b & 63) * 256 + threadIdx.x;     // 0..16383
  int k = idx >> 7, n = idx & 127;
  Wt[n * F + k] = f2bf(W[idx]);
}

// ---------------- single-pass slotted binning (R9 block-level cursors) ----------------
// Blocks [0,NBA): dst -> uint2{payload, fineKey} into slotted D regions (64 B runs).
// Blocks [NBA,NBA+NBS): src -> 1 B fine keys into S regions.
__global__ __launch_bounds__(256) void bin_edges(
    const int* __restrict__ src, const int* __restrict__ dst,
    const float* __restrict__ ew, int E,
    int* __restrict__ cursorD, int* __restrict__ cursorS,
    uint2* __restrict__ slotD, uchar* __restrict__ srcF) {
  __shared__ int cnt[4][COARSE];
  __shared__ int base[COARSE];
  bool isD = blockIdx.x < NBA;
  int blk = isD ? blockIdx.x : blockIdx.x - NBA;
  int nblk = isD ? NBA : NBS;
  const int* key = isD ? dst : src;
  int* cursor = isD ? cursorD : cursorS;
  int wave = threadIdx.x >> 6;
  for (int i = threadIdx.x; i < 4 * COARSE; i += 256) ((int*)cnt)[i] = 0;
  __syncthreads();
  int chunk = (E + nblk - 1) / nblk;
  int s0 = blk * chunk, s1 = min(E, s0 + chunk);
  for (int i = s0 + threadIdx.x; i < s1; i += 256)
    atomicAdd(&cnt[wave][key[i] >> 8], 1);
  __syncthreads();
  if (threadIdx.x < COARSE) {
    int b = threadIdx.x;
    int tot = cnt[0][b] + cnt[1][b] + cnt[2][b] + cnt[3][b];
    base[b] = tot ? atomicAdd(&cursor[b], tot) : 0;
    cnt[0][b] = 0;  // reuse row 0 as block-level scatter cursor
  }
  __syncthreads();
  if (isD) {
    for (int i = s0 + threadIdx.x; i < s1; i += 256) {
      int d = dst[i];
      int bin = d >> 8;
      int p = base[bin] + atomicAdd(&cnt[0][bin], 1);
      if (p < CAP_BIN) {
        uint2 v;
        v.x = (uint)(src[i] & 0xffff) | ((uint)f2bf(ew[i]) << 16);
        v.y = (uint)(d & 255);
        slotD[(size_t)bin * CAP_BIN + p] = v;
      }
    }
  } else {
    for (int i = s0 + threadIdx.x; i < s1; i += 256) {
      int s = src[i];
      int bin = s >> 8;
      int p = base[bin] + atomicAdd(&cnt[0][bin], 1);
      if (p < CAP_BIN) srcF[(size_t)bin * CAP_BIN + p] = (uchar)(s & 255);
    }
  }
}

// ---------------- per-bucket fine sort -> 4-aligned CSR rows ----------------
// Blocks [0,COARSE): D phase. Blocks [COARSE,2*COARSE): S phase (outNorm).
__global__ __launch_bounds__(1024) void bucket_csr(
    const uint2* __restrict__ slotD, const int* __restrict__ cursorD,
    int2* __restrict__ rowRange, float* __restrict__ inNorm, uint* __restrict__ csr,
    const uchar* __restrict__ srcF, const int* __restrict__ cursorS,
    float* __restrict__ outNorm) {
  __shared__ int hist[256], base[256], cur[256];
  int t = threadIdx.x;
  if (blockIdx.x >= COARSE) {   // ---- S phase: outNorm ----
    int b = blockIdx.x - COARSE;
    int lo = b * CAP_BIN;
    int cntS = min(cursorS[b], CAP_BIN);
    if (t < 256) hist[t] = 0;
    __syncthreads();
    for (int i = lo + t; i < lo + cntS; i += 1024)
      atomicAdd(&hist[srcF[i]], 1);
    __syncthreads();
    if (t < 256) outNorm[b * 256 + t] = rsqrtf((float)max(hist[t], 1));
    return;
  }
  // ---- D phase ----
  int b = blockIdx.x;
  int lo = b * CAP_BIN;
  int cntD = min(cursorD[b], CAP_BIN);
  int hi = lo + cntD;
  if (t < 256) hist[t] = 0;
  __syncthreads();
  for (int i = lo + t; i < hi; i += 1024)
    atomicAdd(&hist[slotD[i].y], 1);
  __syncthreads();
  if (t < 256) base[t] = (hist[t] + 3) & ~3;
  __syncthreads();
  for (int off = 1; off < 256; off <<= 1) {
    int x = 0;
    if (t < 256 && t >= off) x = base[t - off];
    __syncthreads();
    if (t < 256) base[t] += x;
    __syncthreads();
  }
  if (t < 256) {
    int v = hist[t];
    int sz4 = (v + 3) & ~3;
    int st = b * CAP_CSR + base[t] - sz4;
    base[t] = st;
    cur[t] = 0;
    int node = b * 256 + t;
    rowRange[node] = make_int2(st, v);
    inNorm[node] = rsqrtf((float)max(v, 1));
  }
  __syncthreads();
  for (int i = lo + t; i < hi; i += 1024) {
    uint2 v = slotD[i];
    int fine = v.y;
    int p = base[fine] + atomicAdd(&cur[fine], 1);
    csr[p] = v.x;
  }
}

// ---------------- MFMA GEMM ----------------
template <bool BF16IN>
__global__ __launch_bounds__(256) void gemm_mfma(
    const void* __restrict__ Xv, const float* __restrict__ scale,
    const ushort* __restrict__ Wt, ushort* __restrict__ Y) {
  __shared__ ushort sA[128 * 136];
  __shared__ ushort sB[128 * 136];
  int t = threadIdx.x;
  int row0 = blockIdx.x * 128;

  {  // stage A
    int r = t >> 1, hf = t & 1;
    ushort* ap = sA + r * 136 + hf * 64;
    if (BF16IN) {
      const ushort* xp = (const ushort*)Xv + (size_t)(row0 + r) * F + hf * 64;
#pragma unroll
      for (int j = 0; j < 8; ++j)
        *(ushort8*)(ap + j * 8) = *(const ushort8*)(xp + j * 8);
    } else {
      const float* xp = (const float*)Xv + (size_t)(row0 + r) * F + hf * 64;
      float s = scale[row0 + r];
#pragma unroll
      for (int j = 0; j < 8; ++j) {
        float4 v0 = *(const float4*)(xp + j * 8);
        float4 v1 = *(const float4*)(xp + j * 8 + 4);
        ushort8 o;
        o[0] = f2bf(v0.x * s); o[1] = f2bf(v0.y * s); o[2] = f2bf(v0.z * s); o[3] = f2bf(v0.w * s);
        o[4] = f2bf(v1.x * s); o[5] = f2bf(v1.y * s); o[6] = f2bf(v1.z * s); o[7] = f2bf(v1.w * s);
        *(ushort8*)(ap + j * 8) = o;
      }
    }
  }
  {  // stage B
    int n = t >> 1, hf = t & 1;
    const ushort* wp = Wt + n * F + hf * 64;
    ushort* bp = sB + n * 136 + hf * 64;
#pragma unroll
    for (int j = 0; j < 8; ++j)
      *(ushort8*)(bp + j * 8) = *(const ushort8*)(wp + j * 8);
  }
  __syncthreads();

  int lane = t & 63, wave = t >> 6;
  int quad = lane >> 4, l16 = lane & 15;
  int mrow0 = wave * 32;

  floatx4 acc[2][8];
#pragma unroll
  for (int a = 0; a < 2; ++a)
#pragma unroll
    for (int c = 0; c < 8; ++c) acc[a][c] = (floatx4){0.f, 0.f, 0.f, 0.f};

#pragma unroll
  for (int kc = 0; kc < 128; kc += 32) {
    short8 afrag[2], bfrag[8];
#pragma unroll
    for (int a = 0; a < 2; ++a)
      afrag[a] = *(const short8*)(sA + (mrow0 + a * 16 + l16) * 136 + kc + quad * 8);
#pragma unroll
    for (int c = 0; c < 8; ++c)
      bfrag[c] = *(const short8*)(sB + (c * 16 + l16) * 136 + kc + quad * 8);
#pragma unroll
    for (int a = 0; a < 2; ++a)
#pragma unroll
      for (int c = 0; c < 8; ++c)
        acc[a][c] = __builtin_amdgcn_mfma_f32_16x16x32_bf16(afrag[a], bfrag[c], acc[a][c], 0, 0, 0);
  }

#pragma unroll
  for (int a = 0; a < 2; ++a)
#pragma unroll
    for (int c = 0; c < 8; ++c)
#pragma unroll
      for (int r = 0; r < 4; ++r) {
        int row = row0 + mrow0 + a * 16 + quad * 4 + r;
        int col = c * 16 + l16;
        Y[(size_t)row * F + col] = f2bf(acc[a][c][r]);
      }
}

// ---------------- SpMM v6: 2 nodes/wave, deep-ILP gather ----------------
// One 64-lane wave handles 2 dst nodes; lane holds dims {2*lane,2*lane+1} of
// both rows. Joint unroll-8 over both rows = 16 gathers + 4 uint4 edge loads
// in flight; per-node drains (8/4/predicated-tail). Rows are 4-aligned.

template <bool EW, bool NB, bool RELU, bool PS, bool OUT_BF16>
__global__ __launch_bounds__(256) void spmm(
    const ushort* __restrict__ hb, const int2* __restrict__ rowRange,
    const uint* __restrict__ csr, const float* __restrict__ inNorm,
    const float* __restrict__ bias, const float* __restrict__ postScale,
    void* __restrict__ outv) {
  int wave = threadIdx.x >> 6;
  int lane = threadIdx.x & 63;
  int n0 = blockIdx.x * 8 + wave * 2;
  int n1 = n0 + 1;
  int2 rA = rowRange[n0];
  int2 rB = rowRange[n1];

#define EDGE(e, X, Y)                                                          \
  {                                                                            \
    uint w = *((const uint*)(hb + ((size_t)((e) & 0xffffu) << 7)) + lane);     \
    float q = EW ? __uint_as_float((e) & 0xffff0000u) : 1.f;                   \
    X = fmaf(__uint_as_float(w << 16), q, X);                                  \
    Y = fmaf(__uint_as_float(w & 0xffff0000u), q, Y);                          \
  }
#define DO4(c, X, Y) \
  EDGE((c).x, X[0], Y[0]) EDGE((c).y, X[1], Y[1]) EDGE((c).z, X[2], Y[2]) EDGE((c).w, X[3], Y[3])

  float AX[4] = {0.f, 0.f, 0.f, 0.f}, AY[4] = {0.f, 0.f, 0.f, 0.f};
  float BX[4] = {0.f, 0.f, 0.f, 0.f}, BY[4] = {0.f, 0.f, 0.f, 0.f};
  int iA = 0, iB = 0;
  int lA = rA.y, lB = rB.y;

  // joint main loop: 16 gathers in flight
  while (iA + 8 <= lA && iB + 8 <= lB) {
    uint4 a0 = *(const uint4*)(csr + rA.x + iA);
    uint4 a1 = *(const uint4*)(csr + rA.x + iA + 4);
    uint4 b0 = *(const uint4*)(csr + rB.x + iB);
    uint4 b1 = *(const uint4*)(csr + rB.x + iB + 4);
    DO4(a0, AX, AY) DO4(a1, AX, AY) DO4(b0, BX, BY) DO4(b1, BX, BY)
    iA += 8; iB += 8;
  }
  // drain A
  while (iA + 8 <= lA) {
    uint4 a0 = *(const uint4*)(csr + rA.x + iA);
    uint4 a1 = *(const uint4*)(csr + rA.x + iA + 4);
    DO4(a0, AX, AY) DO4(a1, AX, AY)
    iA += 8;
  }
  if (iA + 4 <= lA) {
    uint4 a0 = *(const uint4*)(csr + rA.x + iA);
    DO4(a0, AX, AY)
    iA += 4;
  }
  if (iA < lA) {   // 1..3 left; row padded to mult-of-4 -> uint4 safe
    uint4 c = *(const uint4*)(csr + rA.x + iA);
    uint ee[4] = {c.x, c.y, c.z, c.w};
    int r = lA - iA;
#pragma unroll
    for (int j = 0; j < 3; ++j)
      if (j < r) EDGE(ee[j], AX[j], AY[j])
  }
  // drain B
  while (iB + 8 <= lB) {
    uint4 b0 = *(const uint4*)(csr + rB.x + iB);
    uint4 b1 = *(const uint4*)(csr + rB.x + iB + 4);
    DO4(b0, BX, BY) DO4(b1, BX, BY)
    iB += 8;
  }
  if (iB + 4 <= lB) {
    uint4 b0 = *(const uint4*)(csr + rB.x + iB);
    DO4(b0, BX, BY)
    iB += 4;
  }
  if (iB < lB) {
    uint4 c = *(const uint4*)(csr + rB.x + iB);
    uint ee[4] = {c.x, c.y, c.z, c.w};
    int r = lB - iB;
#pragma unroll
    for (int j = 0; j < 3; ++j)
      if (j < r) EDGE(ee[j], BX[j], BY[j])
  }
#undef DO4
#undef EDGE

  float rxA = (AX[0] + AX[1]) + (AX[2] + AX[3]);
  float ryA = (AY[0] + AY[1]) + (AY[2] + AY[3]);
  float rxB = (BX[0] + BX[1]) + (BX[2] + BX[3]);
  float ryB = (BY[0] + BY[1]) + (BY[2] + BY[3]);
  if (NB) {
    float2 bv = *((const float2*)bias + lane);
    float scA = inNorm[n0], scB = inNorm[n1];
    rxA = fmaf(rxA, scA, bv.x); ryA = fmaf(ryA, scA, bv.y);
    rxB = fmaf(rxB, scB, bv.x); ryB = fmaf(ryB, scB, bv.y);
    if (RELU) {
      rxA = fmaxf(rxA, 0.f); ryA = fmaxf(ryA, 0.f);
      rxB = fmaxf(rxB, 0.f); ryB = fmaxf(ryB, 0.f);
    }
    if (PS) {
      float oA = postScale[n0], oB = postScale[n1];
      rxA *= oA; ryA *= oA; rxB *= oB; ryB *= oB;
    }
  }
  if (OUT_BF16) {
    uint pA = ((uint)f2bf(ryA) << 16) | (uint)f2bf(rxA);
    uint pB = ((uint)f2bf(ryB) << 16) | (uint)f2bf(rxB);
    *((uint*)outv + ((size_t)n0 << 6) + lane) = pA;
    *((uint*)outv + ((size_t)n1 << 6) + lane) = pB;
  } else {
    float2 vA = {rxA, ryA};
    float2 vB = {rxB, ryB};
    *((float2*)outv + ((size_t)n0 << 6) + lane) = vA;
    *((float2*)outv + ((size_t)n1 << 6) + lane) = vB;
  }
}

// ---------------- launch ----------------

extern "C" void kernel_launch(void* const* d_in, const int* in_sizes, int n_in,
                              void* d_out, int out_size, void* d_ws, size_t ws_size,
                              hipStream_t stream) {
  const float* feat = (const float*)d_in[0];
  const float* ew   = (const float*)d_in[1];
  const float* W1   = (const float*)d_in[2];
  const float* b1   = (const float*)d_in[3];
  const float* W2   = (const float*)d_in[4];
  const float* b2   = (const float*)d_in[5];
  const int*   src  = (const int*)d_in[6];
  const int*   dst  = (const int*)d_in[7];
  const int N = in_sizes[0] / F;   // 65536
  const int E = in_sizes[6];
  float* out = (float*)d_out;

  char* ws = (char*)d_ws;
  size_t off = 0;
  auto alloc = [&](size_t bytes) {
    void* p = ws + off;
    off += (bytes + 255) & ~(size_t)255;
    return p;
  };
  int2*   rowRange = (int2*)alloc((size_t)N * 8);
  float*  inNorm   = (float*)alloc((size_t)N * 4);
  float*  outNorm  = (float*)alloc((size_t)N * 4);
  ushort* W1t      = (ushort*)alloc((size_t)F * F * 2);
  ushort* W2t      = (ushort*)alloc((size_t)F * F * 2);
  int*    cursorD  = (int*)alloc(COARSE * 4);
  int*    cursorS  = (int*)alloc(COARSE * 4);
  uint*   csr      = (uint*)alloc((size_t)COARSE * CAP_CSR * 4);
  ushort* bufAb    = (ushort*)alloc((size_t)N * F * 2);
  ushort* bufBb    = (ushort*)alloc((size_t)N * F * 2);
  ushort* bufCb    = (ushort*)alloc((size_t)N * F * 2);
  if (off > ws_size) return;

  uint2* slotD;
  uchar* srcF;
  {
    char* tp = (char*)bufBb;
    size_t toff = 0;
    auto talloc = [&](size_t bytes) {
      void* p = tp + toff;
      toff += (bytes + 255) & ~(size_t)255;
      return p;
    };
    slotD = (uint2*)talloc((size_t)COARSE * CAP_BIN * 8);
    srcF  = (uchar*)talloc((size_t)COARSE * CAP_BIN);
  }

  w_prep<<<128, 256, 0, stream>>>(W1, W2, W1t, W2t, cursorD, cursorS);
  bin_edges<<<NBA + NBS, 256, 0, stream>>>(src, dst, ew, E, cursorD, cursorS, slotD, srcF);
  bucket_csr<<<2 * COARSE, 1024, 0, stream>>>(slotD, cursorD, rowRange, inNorm, csr,
                                              srcF, cursorS, outNorm);

  // layer 1: h1pre = bf16( relu(SpMM(bf16((feat*outNorm)@W1)) * inNorm + b1) * outNorm )
  gemm_mfma<false><<<N / 128, 256, 0, stream>>>(feat, outNorm, W1t, bufAb);
  spmm<false, true, true, true, true><<<N / 8, 256, 0, stream>>>(
      bufAb, rowRange, csr, inNorm, b1, outNorm, bufBb);
  // layer 2: h2 = bf16( SpMM(bf16(h1pre@W2)) * inNorm + b2 )
  gemm_mfma<true><<<N / 128, 256, 0, stream>>>(bufBb, nullptr, W2t, bufAb);
  spmm<false, true, false, false, true><<<N / 8, 256, 0, stream>>>(
      bufAb, rowRange, csr, inNorm, b2, nullptr, bufCb);
  // final: out = segment_sum(h2[src] * eweight, dst)   [fp32 out]
  spmm<true, false, false, false, false><<<N / 8, 256, 0, stream>>>(
      bufCb, rowRange, csr, nullptr, nullptr, nullptr, out);
}